// Round 1
// baseline (1008.386 us; speedup 1.0000x reference)
//
#include <hip/hip_runtime.h>
#include <math.h>

// ---------------------------------------------------------------------------
// 2-layer GCN. R13: delete the CSR ordering entirely.
// Aggregation is a commutative sum, so the only thing agg needs is edges
// bucketed by dst — which scatterA's tmp already provides. csrbuild (scan +
// ordered scatter) is replaced by a 5us degree histogram; agg1/agg2 become
// bucket-parallel LDS fp32 atomic accumulators (512 nodes/bucket):
//  - agg1_acc: 128KB LDS acc[512][68] (stride 68: bank=(4d+f)%32 spreads the
//    per-edge 4-bank set by d%8 -> ~2-way). 8 lanes/edge gather h1s rows as
//    independent uint4 loads (MLP >> old serial CSR walk at 23% HBM).
//    Epilogue fuses self-loop + b1 + lrelu + 64->16 MLP (2 thr/node).
//  - agg2_acc: acc[512][17] (35KB), 2 lanes/edge, per-thread log_softmax.
// tmp now lives until agg2 -> t gets its own allocation (csr freed, net win).
// ---------------------------------------------------------------------------

#define CHUNK 4096        // edges per scatterA block
#define BSHIFT 9          // 512 nodes per bucket
#define BMASK 511
#define CAP 9216          // tmp slots per bucket (mean 8192, +11 sigma)
#define ASTRIDE 68        // acc row stride (f32): pad 64->68 for bank spread

typedef __bf16 bf16x8 __attribute__((ext_vector_type(8)));
typedef float f32x4 __attribute__((ext_vector_type(4)));

__device__ __forceinline__ unsigned f2b(float f) {  // fp32 -> bf16 bits (RNE)
  unsigned u = __float_as_uint(f);
  return (u + 0x7FFF + ((u >> 16) & 1)) >> 16;
}
__device__ __forceinline__ float blo(unsigned u) { return __uint_as_float(u << 16); }
__device__ __forceinline__ float bhi(unsigned u) { return __uint_as_float(u & 0xffff0000u); }
__device__ __forceinline__ void atomAdd2(float* p, unsigned u) {
  atomicAdd(p, blo(u));       // even feature (low u16)
  atomicAdd(p + 1, bhi(u));   // odd feature (high u16)
}

__global__ void binit_kernel(int* __restrict__ gbcursor, int nbc) {
  int b = blockIdx.x * 256 + threadIdx.x;
  if (b < nbc) gbcursor[b] = b * CAP;
}

// Block multisplit: pass1 LDS bucket hist; one global atomic per (block,bucket)
// reserves a segment; pass2 places edges via LDS cursors. pack=(src<<9)|(dst&511).
__global__ __launch_bounds__(256) void scatterA_kernel(const int* __restrict__ src,
                                                       const int* __restrict__ dst,
                                                       int E, int nbc,
                                                       int* __restrict__ gbcursor,
                                                       int* __restrict__ tmp) {
  __shared__ int hist[256];
  __shared__ int segcur[256];
  int tid = threadIdx.x;
  int estart = blockIdx.x * CHUNK;
  int eend = min(E, estart + CHUNK);
  hist[tid] = 0;
  __syncthreads();
  for (int i = estart + tid; i < eend; i += 256)
    atomicAdd(&hist[dst[i] >> BSHIFT], 1);
  __syncthreads();
  if (tid < nbc) {
    int c = hist[tid];
    segcur[tid] = c ? atomicAdd(&gbcursor[tid], c) : 0;
  }
  __syncthreads();
  for (int i = estart + tid; i < eend; i += 256) {
    int d = dst[i];
    int b = d >> BSHIFT;
    int pos = atomicAdd(&segcur[b], 1);
    if (pos < (b + 1) * CAP)  // statistically impossible overflow guard
      tmp[pos] = (src[i] << BSHIFT) | (d & BMASK);
  }
}

// Per-bucket in-degree histogram -> dinv (the only csrbuild output still needed).
__global__ __launch_bounds__(512) void degcnt_kernel(const int* __restrict__ tmp,
                                                     const int* __restrict__ gbcursor,
                                                     float* __restrict__ dinv, int n) {
  __shared__ int nh[512];
  int b = blockIdx.x, tid = threadIdx.x;
  nh[tid] = 0;
  __syncthreads();
  int base = b * CAP;
  int count = min(gbcursor[b] - base, CAP);
  for (int i = tid; i < count; i += 512) atomicAdd(&nh[tmp[base + i] & BMASK], 1);
  __syncthreads();
  int v = (b << BSHIFT) + tid;
  if (v < n) dinv[v] = rsqrtf((float)(nh[tid] + 1));
}

// h1s[row] = bf16x2-packed dinv[row] * (x[row] @ W1), via MFMA (R9-proven).
__global__ __launch_bounds__(256, 4) void gemm1_kernel(const float* __restrict__ x,
                                                       const float* __restrict__ W1,
                                                       const float* __restrict__ dinv,
                                                       unsigned* __restrict__ h1s, int n) {
  __shared__ unsigned lds_u[64 * 68 * 2];
  unsigned* xs = lds_u;
  unsigned* wt = lds_u + 64 * 68;
  int tid = threadIdx.x;
  int vb = blockIdx.x * 64;
  int nrows = min(64, n - vb);

  // stage x: coalesced float4 loads, pack to bf16x2
  const float4* xg = (const float4*)(x + (size_t)vb * 128);
#pragma unroll
  for (int it = 0; it < 8; ++it) {
    int idx = it * 256 + tid;
    int r = idx >> 5, c2 = idx & 31;
    float4 vv = make_float4(0.f, 0.f, 0.f, 0.f);
    if (r < nrows) vv = xg[idx];
    xs[r * 68 + c2 * 2] = (f2b(vv.y) << 16) | f2b(vv.x);
    xs[r * 68 + c2 * 2 + 1] = (f2b(vv.w) << 16) | f2b(vv.z);
  }
  // stage W1^T: wt16[n][k] bf16, stride 136 u16 (= 68 u32)
  unsigned short* wt16 = (unsigned short*)wt;
  const float4* wg = (const float4*)W1;
#pragma unroll
  for (int it = 0; it < 8; ++it) {
    int idx = it * 256 + tid;          // [0,2048): k = idx>>4, n0 = (idx&15)*4
    int k = idx >> 4, n0 = (idx & 15) * 4;
    float4 wv = wg[idx];
    wt16[(n0 + 0) * 136 + k] = (unsigned short)f2b(wv.x);
    wt16[(n0 + 1) * 136 + k] = (unsigned short)f2b(wv.y);
    wt16[(n0 + 2) * 136 + k] = (unsigned short)f2b(wv.z);
    wt16[(n0 + 3) * 136 + k] = (unsigned short)f2b(wv.w);
  }
  __syncthreads();

  int lane = tid & 63, wid = tid >> 6;
  int m16 = lane & 15, quad = lane >> 4;
  const unsigned* xp = xs + (wid * 16 + m16) * 68 + quad * 4;
  const unsigned* wp = wt + m16 * 68 + quad * 4;
  f32x4 acc[4] = {};
#pragma unroll
  for (int ks = 0; ks < 4; ++ks) {
    bf16x8 a = *(const bf16x8*)(xp + ks * 16);
#pragma unroll
    for (int nt = 0; nt < 4; ++nt) {
      bf16x8 b = *(const bf16x8*)(wp + nt * 16 * 68 + ks * 16);
      acc[nt] = __builtin_amdgcn_mfma_f32_16x16x32_bf16(a, b, acc[nt], 0, 0, 0);
    }
  }
  // epilogue: C[row = quad*4+reg][col = nt*16+m16]; fold dinv, pack bf16
  int rbase = vb + wid * 16 + quad * 4;
  float dvv[4];
#pragma unroll
  for (int reg = 0; reg < 4; ++reg) {
    int row = rbase + reg;
    dvv[reg] = (row < n) ? dinv[row] : 0.f;
  }
  unsigned short* h16 = (unsigned short*)h1s;
#pragma unroll
  for (int nt = 0; nt < 4; ++nt) {
    int col = nt * 16 + m16;
#pragma unroll
    for (int reg = 0; reg < 4; ++reg) {
      int row = rbase + reg;
      if (row < n)
        h16[(size_t)row * 64 + col] = (unsigned short)f2b(dvv[reg] * acc[nt][reg]);
    }
  }
}

// One 1024-thr block per bucket. Edge phase: 8 lanes/edge (c = uint4 slot),
// independent 16B gathers of h1s[src] -> LDS fp32 atomic accumulate on
// acc[d&511][f]. Epilogue: 2 thr/node fuse self-loop + b1 + lrelu + MLP(64->16),
// pack t[v] = bf16(dinv[v] * p).
__global__ __launch_bounds__(1024) void agg1_acc_kernel(const int* __restrict__ tmp,
                                                        const int* __restrict__ gbcursor,
                                                        const uint4* __restrict__ h1s4,
                                                        const float* __restrict__ dinv,
                                                        const float* __restrict__ b1,
                                                        const float* __restrict__ W2,
                                                        unsigned* __restrict__ t, int n) {
  __shared__ float acc[512 * ASTRIDE];   // 139,264 B
  __shared__ float W2s[64 * 16];         // 4 KB
  __shared__ float b1s[64];
  int b = blockIdx.x, tid = threadIdx.x;
  int base = b * CAP;
  int count = min(gbcursor[b] - base, CAP);
  for (int i = tid; i < 512 * ASTRIDE; i += 1024) acc[i] = 0.f;
  W2s[tid] = W2[tid];                    // 64*16 == 1024 == blockDim
  if (tid < 64) b1s[tid] = b1[tid];
  __syncthreads();

  int e = tid >> 3, c = tid & 7;         // 128 edges per pass
#pragma unroll 2
  for (int i = e; i < count; i += 128) {
    int pk = tmp[base + i];
    int s = pk >> BSHIFT, d = pk & BMASK;
    uint4 g = h1s4[(size_t)s * 8 + c];   // 8 lanes -> 128B contiguous row
    float* ap = acc + d * ASTRIDE + c * 8;
    atomAdd2(ap, g.x);
    atomAdd2(ap + 2, g.y);
    atomAdd2(ap + 4, g.z);
    atomAdd2(ap + 6, g.w);
  }
  __syncthreads();

  // epilogue: thread pair (v2, half); half owns features half*32..+31
  int v2 = tid >> 1, half = tid & 1;
  int v = (b << BSHIFT) + v2;
  bool valid = v < n;
  float dv = valid ? dinv[v] : 0.f;
  const uint4* selfp = h1s4 + (size_t)(valid ? v : 0) * 8 + half * 4;
  const float* arow = acc + v2 * ASTRIDE + half * 32;
  float av[32];
#pragma unroll
  for (int q = 0; q < 4; ++q) {
    uint4 g = selfp[q];
    float4 a0 = *(const float4*)(arow + q * 8);
    float4 a1 = *(const float4*)(arow + q * 8 + 4);
    int fb = half * 32 + q * 8;
    float z;
    z = fmaf(dv, a0.x + blo(g.x), b1s[fb + 0]); av[q * 8 + 0] = fmaxf(z, 0.2f * z);
    z = fmaf(dv, a0.y + bhi(g.x), b1s[fb + 1]); av[q * 8 + 1] = fmaxf(z, 0.2f * z);
    z = fmaf(dv, a0.z + blo(g.y), b1s[fb + 2]); av[q * 8 + 2] = fmaxf(z, 0.2f * z);
    z = fmaf(dv, a0.w + bhi(g.y), b1s[fb + 3]); av[q * 8 + 3] = fmaxf(z, 0.2f * z);
    z = fmaf(dv, a1.x + blo(g.z), b1s[fb + 4]); av[q * 8 + 4] = fmaxf(z, 0.2f * z);
    z = fmaf(dv, a1.y + bhi(g.z), b1s[fb + 5]); av[q * 8 + 5] = fmaxf(z, 0.2f * z);
    z = fmaf(dv, a1.z + blo(g.w), b1s[fb + 6]); av[q * 8 + 6] = fmaxf(z, 0.2f * z);
    z = fmaf(dv, a1.w + bhi(g.w), b1s[fb + 7]); av[q * 8 + 7] = fmaxf(z, 0.2f * z);
  }
  float p[16];
#pragma unroll
  for (int j = 0; j < 16; ++j) p[j] = 0.f;
#pragma unroll
  for (int q = 0; q < 32; ++q) {
    float a = av[q];
    const float4* wr = (const float4*)(W2s + (half * 32 + q) * 16);
    float4 w0 = wr[0], w1 = wr[1], w2v = wr[2], w3 = wr[3];
    p[0] = fmaf(a, w0.x, p[0]);  p[1] = fmaf(a, w0.y, p[1]);
    p[2] = fmaf(a, w0.z, p[2]);  p[3] = fmaf(a, w0.w, p[3]);
    p[4] = fmaf(a, w1.x, p[4]);  p[5] = fmaf(a, w1.y, p[5]);
    p[6] = fmaf(a, w1.z, p[6]);  p[7] = fmaf(a, w1.w, p[7]);
    p[8] = fmaf(a, w2v.x, p[8]); p[9] = fmaf(a, w2v.y, p[9]);
    p[10] = fmaf(a, w2v.z, p[10]); p[11] = fmaf(a, w2v.w, p[11]);
    p[12] = fmaf(a, w3.x, p[12]); p[13] = fmaf(a, w3.y, p[13]);
    p[14] = fmaf(a, w3.z, p[14]); p[15] = fmaf(a, w3.w, p[15]);
  }
#pragma unroll
  for (int j = 0; j < 16; ++j) p[j] += __shfl_xor(p[j], 1, 64);  // pair = lanes 2v2,2v2+1
  if (valid) {
    int jb = half * 8;
    uint4 o;
    o.x = (f2b(dv * p[jb + 1]) << 16) | f2b(dv * p[jb + 0]);
    o.y = (f2b(dv * p[jb + 3]) << 16) | f2b(dv * p[jb + 2]);
    o.z = (f2b(dv * p[jb + 5]) << 16) | f2b(dv * p[jb + 4]);
    o.w = (f2b(dv * p[jb + 7]) << 16) | f2b(dv * p[jb + 6]);
    ((uint4*)t)[(size_t)v * 2 + half] = o;
  }
}

// Same structure for layer 2: 2 lanes/edge (32B t rows), acc[512][17] (stride 17
// is odd -> bank=(17d+f)%32 uniform). Epilogue: 1 thr/node log_softmax.
__global__ __launch_bounds__(1024) void agg2_acc_kernel(const int* __restrict__ tmp,
                                                        const int* __restrict__ gbcursor,
                                                        const uint4* __restrict__ t4,
                                                        const float* __restrict__ dinv,
                                                        const float* __restrict__ b2,
                                                        float* __restrict__ out, int n) {
  __shared__ float acc[512 * 17];
  int b = blockIdx.x, tid = threadIdx.x;
  int base = b * CAP;
  int count = min(gbcursor[b] - base, CAP);
  for (int i = tid; i < 512 * 17; i += 1024) acc[i] = 0.f;
  __syncthreads();

  int e = tid >> 1, c = tid & 1;         // 512 edges per pass
#pragma unroll 2
  for (int i = e; i < count; i += 512) {
    int pk = tmp[base + i];
    int s = pk >> BSHIFT, d = pk & BMASK;
    uint4 g = t4[(size_t)s * 2 + c];
    float* ap = acc + d * 17 + c * 8;
    atomAdd2(ap, g.x);
    atomAdd2(ap + 2, g.y);
    atomAdd2(ap + 4, g.z);
    atomAdd2(ap + 6, g.w);
  }
  __syncthreads();

  if (tid < 512) {
    int v = (b << BSHIFT) + tid;
    if (v < n) {
      float dv = dinv[v];
      uint4 g0 = t4[(size_t)v * 2];
      uint4 g1 = t4[(size_t)v * 2 + 1];
      const float* ar = acc + tid * 17;
      float4 bb0 = ((const float4*)b2)[0], bb1 = ((const float4*)b2)[1];
      float4 bb2 = ((const float4*)b2)[2], bb3 = ((const float4*)b2)[3];
      float z[16];
      z[0] = fmaf(dv, ar[0] + blo(g0.x), bb0.x);
      z[1] = fmaf(dv, ar[1] + bhi(g0.x), bb0.y);
      z[2] = fmaf(dv, ar[2] + blo(g0.y), bb0.z);
      z[3] = fmaf(dv, ar[3] + bhi(g0.y), bb0.w);
      z[4] = fmaf(dv, ar[4] + blo(g0.z), bb1.x);
      z[5] = fmaf(dv, ar[5] + bhi(g0.z), bb1.y);
      z[6] = fmaf(dv, ar[6] + blo(g0.w), bb1.z);
      z[7] = fmaf(dv, ar[7] + bhi(g0.w), bb1.w);
      z[8] = fmaf(dv, ar[8] + blo(g1.x), bb2.x);
      z[9] = fmaf(dv, ar[9] + bhi(g1.x), bb2.y);
      z[10] = fmaf(dv, ar[10] + blo(g1.y), bb2.z);
      z[11] = fmaf(dv, ar[11] + bhi(g1.y), bb2.w);
      z[12] = fmaf(dv, ar[12] + blo(g1.z), bb3.x);
      z[13] = fmaf(dv, ar[13] + bhi(g1.z), bb3.y);
      z[14] = fmaf(dv, ar[14] + blo(g1.w), bb3.z);
      z[15] = fmaf(dv, ar[15] + bhi(g1.w), bb3.w);
      float mx = z[0];
#pragma unroll
      for (int q = 1; q < 16; ++q) mx = fmaxf(mx, z[q]);
      float ss = 0.f;
#pragma unroll
      for (int q = 0; q < 16; ++q) ss += expf(z[q] - mx);
      float lg = mx + logf(ss);
      float4* o = (float4*)out + (size_t)v * 4;
      o[0] = make_float4(z[0] - lg, z[1] - lg, z[2] - lg, z[3] - lg);
      o[1] = make_float4(z[4] - lg, z[5] - lg, z[6] - lg, z[7] - lg);
      o[2] = make_float4(z[8] - lg, z[9] - lg, z[10] - lg, z[11] - lg);
      o[3] = make_float4(z[12] - lg, z[13] - lg, z[14] - lg, z[15] - lg);
    }
  }
}

extern "C" void kernel_launch(void* const* d_in, const int* in_sizes, int n_in,
                              void* d_out, int out_size, void* d_ws, size_t ws_size,
                              hipStream_t stream) {
  const float* x = (const float*)d_in[0];
  const int* edge_index = (const int*)d_in[1];
  const float* W1 = (const float*)d_in[2];
  const float* b1 = (const float*)d_in[3];
  const float* W2 = (const float*)d_in[4];
  const float* b2 = (const float*)d_in[5];
  float* out = (float*)d_out;

  int N_ = in_sizes[0] / 128;
  int E_ = in_sizes[1] / 2;
  const int* src = edge_index;
  const int* dst = edge_index + E_;
  int NBc = (N_ + BMASK) >> BSHIFT;  // 196 buckets of 512 nodes (<= 256)

  char* ws = (char*)d_ws;
  size_t off = 0;
  auto take = [&](size_t bytes) {
    void* p = ws + off;
    off += (bytes + 255) & ~(size_t)255;
    return p;
  };
  unsigned* h1s = (unsigned*)take((size_t)N_ * 32 * 4);
  int* tmp = (int*)take((size_t)NBc * CAP * 4);      // live until agg2 now
  unsigned* t = (unsigned*)take((size_t)N_ * 8 * 4); // no longer aliases tmp
  float* dinv = (float*)take((size_t)N_ * 4);
  int* gbcursor = (int*)take((size_t)NBc * 4);
  (void)ws_size;

  binit_kernel<<<(NBc + 255) / 256, 256, 0, stream>>>(gbcursor, NBc);
  scatterA_kernel<<<(E_ + CHUNK - 1) / CHUNK, 256, 0, stream>>>(src, dst, E_, NBc,
                                                                gbcursor, tmp);
  degcnt_kernel<<<NBc, 512, 0, stream>>>(tmp, gbcursor, dinv, N_);
  gemm1_kernel<<<(N_ + 63) / 64, 256, 0, stream>>>(x, W1, dinv, h1s, N_);
  agg1_acc_kernel<<<NBc, 1024, 0, stream>>>(tmp, gbcursor, (const uint4*)h1s, dinv,
                                            b1, W2, t, N_);
  agg2_acc_kernel<<<NBc, 1024, 0, stream>>>(tmp, gbcursor, (const uint4*)t, dinv,
                                            b2, out, N_);
}